// Round 1
// baseline (2890.242 us; speedup 1.0000x reference)
//
#include <hip/hip_runtime.h>
#include <math.h>

#define NN 100000
#define NE 1600000
#define DIN 256
#define HD 64
#define OUTD 32
#define EMBD 128
#define SLOPE 0.2f

// ---------- helpers ----------
__device__ __forceinline__ unsigned fenc(float f) {
    unsigned u = __float_as_uint(f);
    return (u & 0x80000000u) ? ~u : (u | 0x80000000u);  // monotone float->uint
}
__device__ __forceinline__ float fdec(unsigned u) {
    unsigned v = (u & 0x80000000u) ? (u & 0x7FFFFFFFu) : ~u;
    return __uint_as_float(v);
}
__device__ __forceinline__ float lrelu(float x) { return x > 0.f ? x : SLOPE * x; }

// ---------- kernels ----------

// degree count (incoming edges per dst)
__global__ void k_degree(const int* __restrict__ dst, float* __restrict__ deg) {
    int i = blockIdx.x * blockDim.x + threadIdx.x;
    if (i < NE) atomicAdd(&deg[dst[i]], 1.0f);
}

__global__ void k_invdeg(float* __restrict__ deg) {
    int i = blockIdx.x * blockDim.x + threadIdx.x;
    if (i < NN) deg[i] = 1.0f / fmaxf(deg[i], 1.0f);
}

// fused front: n2v projection + gated input fusion -> h0 [NN,64]
// h = raw_proj + gate * (n2v_p @ ip_w[256:,:])
__global__ void k_front(const float* __restrict__ x, const float* __restrict__ n2v,
                        const float* __restrict__ n2v_w, const float* __restrict__ n2v_b,
                        const float* __restrict__ ip_w, const float* __restrict__ ip_b,
                        const float* __restrict__ gate_w, const float* __restrict__ gate_b,
                        float* __restrict__ h0) {
    __shared__ float sx[DIN];
    __shared__ float sn[EMBD];
    __shared__ float sp[HD];
    int n = blockIdx.x;
    int t = threadIdx.x;  // 64 threads
    ((float4*)sx)[t] = ((const float4*)(x + (size_t)n * DIN))[t];
    ((float2*)sn)[t] = ((const float2*)(n2v + (size_t)n * EMBD))[t];
    __syncthreads();
    float acc = n2v_b[t];
#pragma unroll 4
    for (int k = 0; k < EMBD; k++) acc += sn[k] * n2v_w[k * HD + t];
    sp[t] = acc;
    __syncthreads();
    float g = gate_b[t], raw = ip_b[t], del = 0.f;
#pragma unroll 4
    for (int k = 0; k < DIN; k++) {
        float xv = sx[k];
        g += xv * gate_w[k * HD + t];
        raw += xv * ip_w[k * HD + t];
    }
#pragma unroll 4
    for (int k = 0; k < HD; k++) {
        float pv = sp[k];
        g += pv * gate_w[(DIN + k) * HD + t];
        del += pv * ip_w[(DIN + k) * HD + t];
    }
    g = 1.f / (1.f + expf(-g));
    h0[(size_t)n * HD + t] = raw + g * del;
}

// scatter-add 64-wide rows: acc[dst] += h[src], one wave per edge
__global__ void k_scatter64(const int* __restrict__ src, const int* __restrict__ dst,
                            const float* __restrict__ h, float* __restrict__ acc) {
    int e = (blockIdx.x * blockDim.x + threadIdx.x) >> 6;
    int j = threadIdx.x & 63;
    if (e >= NE) return;
    int s = src[e], d = dst[e];
    atomicAdd(&acc[(size_t)d * HD + j], h[(size_t)s * HD + j]);
}

// SAGE combine: hout = [relu]( (acc*invdeg) @ wl + bl + hin @ wr )
__global__ void k_sage(const float* __restrict__ acc, const float* __restrict__ hin,
                       const float* __restrict__ invdeg,
                       const float* __restrict__ wl, const float* __restrict__ bl,
                       const float* __restrict__ wr, float* __restrict__ hout) {
    __shared__ float sa[HD];
    __shared__ float sh[HD];
    int n = blockIdx.x, t = threadIdx.x;  // 64 threads
    float id = invdeg[n];
    sa[t] = acc[(size_t)n * HD + t] * id;
    sh[t] = hin[(size_t)n * HD + t];
    __syncthreads();
    float o = bl[t];
#pragma unroll 4
    for (int k = 0; k < HD; k++) o += sa[k] * wl[k * HD + t] + sh[k] * wr[k * HD + t];
    hout[(size_t)n * HD + t] = fmaxf(o, 0.f);
}

// GAT transform: xh = h @ w (64->128), plus per-head attention scalars
__global__ void k_gat_xh(const float* __restrict__ h, const float* __restrict__ w,
                         const float* __restrict__ att_s, const float* __restrict__ att_d,
                         float* __restrict__ xh, float* __restrict__ a_s, float* __restrict__ a_d) {
    __shared__ float sh[HD];
    int n = blockIdx.x, t = threadIdx.x;  // 128 threads
    if (t < HD) sh[t] = h[(size_t)n * HD + t];
    __syncthreads();
    float v = 0.f;
#pragma unroll 4
    for (int k = 0; k < HD; k++) v += sh[k] * w[k * 128 + t];
    xh[(size_t)n * 128 + t] = v;
    float ps = v * att_s[t];  // att_s is [2][64] flat = 128
    float pd = v * att_d[t];
#pragma unroll
    for (int off = 32; off; off >>= 1) {
        ps += __shfl_down(ps, off);
        pd += __shfl_down(pd, off);
    }
    if ((t & 63) == 0) {
        a_s[n * 2 + (t >> 6)] = ps;
        a_d[n * 2 + (t >> 6)] = pd;
    }
}

// edge attention max (includes self-loops at ids >= NE)
__global__ void k_emax(const int* __restrict__ src, const int* __restrict__ dst,
                       const float* __restrict__ a_s, const float* __restrict__ a_d,
                       unsigned* __restrict__ emax) {
    int i = blockIdx.x * blockDim.x + threadIdx.x;
    if (i >= NE + NN) return;
    int s, d;
    if (i < NE) { s = src[i]; d = dst[i]; } else { s = d = i - NE; }
    float e0 = lrelu(a_s[s * 2] + a_d[d * 2]);
    float e1 = lrelu(a_s[s * 2 + 1] + a_d[d * 2 + 1]);
    atomicMax(&emax[d * 2], fenc(e0));
    atomicMax(&emax[d * 2 + 1], fenc(e1));
}

// edge attention exp-sum
__global__ void k_esum(const int* __restrict__ src, const int* __restrict__ dst,
                       const float* __restrict__ a_s, const float* __restrict__ a_d,
                       const unsigned* __restrict__ emax, float* __restrict__ esum) {
    int i = blockIdx.x * blockDim.x + threadIdx.x;
    if (i >= NE + NN) return;
    int s, d;
    if (i < NE) { s = src[i]; d = dst[i]; } else { s = d = i - NE; }
    float e0 = lrelu(a_s[s * 2] + a_d[d * 2]);
    float e1 = lrelu(a_s[s * 2 + 1] + a_d[d * 2 + 1]);
    atomicAdd(&esum[d * 2], expf(e0 - fdec(emax[d * 2])));
    atomicAdd(&esum[d * 2 + 1], expf(e1 - fdec(emax[d * 2 + 1])));
}

// edge weighted scatter: acc[dst] += 0.5*(alpha0*xh[src,0,:] + alpha1*xh[src,1,:]); one wave/edge
__global__ void k_gat_scatter(const int* __restrict__ src, const int* __restrict__ dst,
                              const float* __restrict__ a_s, const float* __restrict__ a_d,
                              const unsigned* __restrict__ emax, const float* __restrict__ esum,
                              const float* __restrict__ xh, float* __restrict__ acc) {
    int e = (blockIdx.x * blockDim.x + threadIdx.x) >> 6;
    int j = threadIdx.x & 63;
    if (e >= NE + NN) return;
    int s, d;
    if (e < NE) { s = src[e]; d = dst[e]; } else { s = d = e - NE; }
    float e0 = lrelu(a_s[s * 2] + a_d[d * 2]);
    float e1 = lrelu(a_s[s * 2 + 1] + a_d[d * 2 + 1]);
    float al0 = expf(e0 - fdec(emax[d * 2])) / (esum[d * 2] + 1e-16f);
    float al1 = expf(e1 - fdec(emax[d * 2 + 1])) / (esum[d * 2 + 1] + 1e-16f);
    float v = 0.5f * (al0 * xh[(size_t)s * 128 + j] + al1 * xh[(size_t)s * 128 + 64 + j]);
    atomicAdd(&acc[(size_t)d * HD + j], v);
}

// GAT finalize: h3 = relu(acc + b)
__global__ void k_gat_fin(const float* __restrict__ acc, const float* __restrict__ b,
                          float* __restrict__ hout) {
    int n = blockIdx.x, t = threadIdx.x;  // 64 threads
    hout[(size_t)n * HD + t] = fmaxf(acc[(size_t)n * HD + t] + b[t], 0.f);
}

// final SAGE: out = (acc*invdeg) @ wl(64x32) + bl + hin @ wr(64x32)
__global__ void k_final(const float* __restrict__ acc, const float* __restrict__ hin,
                        const float* __restrict__ invdeg,
                        const float* __restrict__ wl, const float* __restrict__ bl,
                        const float* __restrict__ wr, float* __restrict__ out) {
    __shared__ float sa[HD];
    __shared__ float sh[HD];
    int n = blockIdx.x, t = threadIdx.x;  // 64 threads
    sa[t] = acc[(size_t)n * HD + t] * invdeg[n];
    sh[t] = hin[(size_t)n * HD + t];
    __syncthreads();
    if (t < OUTD) {
        float o = bl[t];
#pragma unroll 4
        for (int k = 0; k < HD; k++) o += sa[k] * wl[k * OUTD + t] + sh[k] * wr[k * OUTD + t];
        out[(size_t)n * OUTD + t] = o;
    }
}

// ---------- launch ----------
extern "C" void kernel_launch(void* const* d_in, const int* in_sizes, int n_in,
                              void* d_out, int out_size, void* d_ws, size_t ws_size,
                              hipStream_t stream) {
    const float* x      = (const float*)d_in[0];
    const int*   eidx   = (const int*)d_in[1];   // [2, NE] int32
    const float* n2v    = (const float*)d_in[2];
    const float* n2v_w  = (const float*)d_in[3];
    const float* n2v_b  = (const float*)d_in[4];
    const float* ip_w   = (const float*)d_in[5];
    const float* ip_b   = (const float*)d_in[6];
    const float* gate_w = (const float*)d_in[7];
    const float* gate_b = (const float*)d_in[8];
    const float* s0_wl  = (const float*)d_in[9];
    const float* s0_bl  = (const float*)d_in[10];
    const float* s0_wr  = (const float*)d_in[11];
    const float* s1_wl  = (const float*)d_in[12];
    const float* s1_bl  = (const float*)d_in[13];
    const float* s1_wr  = (const float*)d_in[14];
    const float* gat_w  = (const float*)d_in[15];
    const float* att_s  = (const float*)d_in[16];
    const float* att_d  = (const float*)d_in[17];
    const float* gat_b  = (const float*)d_in[18];
    const float* f_wl   = (const float*)d_in[19];
    const float* f_bl   = (const float*)d_in[20];
    const float* f_wr   = (const float*)d_in[21];

    const int* src = eidx;
    const int* dst = eidx + NE;

    float* ws = (float*)d_ws;
    float*    A    = ws;                       // NN*64
    float*    B    = A + (size_t)NN * HD;      // NN*64
    float*    C    = B + (size_t)NN * HD;      // NN*64
    float*    X    = C + (size_t)NN * HD;      // NN*128
    float*    deg  = X + (size_t)NN * 128;     // NN
    float*    a_s  = deg + NN;                 // NN*2
    float*    a_d  = a_s + (size_t)NN * 2;     // NN*2
    unsigned* emax = (unsigned*)(a_d + (size_t)NN * 2);  // NN*2
    float*    esum = (float*)(emax + (size_t)NN * 2);    // NN*2

    float* out = (float*)d_out;

    const int BT = 256;
    dim3 b64(64), b128(128), b256(BT);
    int eblk  = (NE + BT - 1) / BT;              // per-thread edge kernels
    int enblk = (NE + NN + BT - 1) / BT;
    int wblk  = (NE + 3) / 4;                    // one wave per edge, 4 waves/block
    int wnblk = (NE + NN + 3) / 4;

    // degree (shared by all SAGE layers)
    hipMemsetAsync(deg, 0, (size_t)NN * 4, stream);
    k_degree<<<eblk, b256, 0, stream>>>(dst, deg);
    k_invdeg<<<(NN + BT - 1) / BT, b256, 0, stream>>>(deg);

    // front fusion -> A (h0)
    k_front<<<NN, b64, 0, stream>>>(x, n2v, n2v_w, n2v_b, ip_w, ip_b, gate_w, gate_b, A);

    // SAGE 0: A -> B
    hipMemsetAsync(C, 0, (size_t)NN * HD * 4, stream);
    k_scatter64<<<wblk, b256, 0, stream>>>(src, dst, A, C);
    k_sage<<<NN, b64, 0, stream>>>(C, A, deg, s0_wl, s0_bl, s0_wr, B);

    // SAGE 1: B -> A
    hipMemsetAsync(C, 0, (size_t)NN * HD * 4, stream);
    k_scatter64<<<wblk, b256, 0, stream>>>(src, dst, B, C);
    k_sage<<<NN, b64, 0, stream>>>(C, B, deg, s1_wl, s1_bl, s1_wr, A);

    // GAT: A -> B
    k_gat_xh<<<NN, b128, 0, stream>>>(A, gat_w, att_s, att_d, X, a_s, a_d);
    hipMemsetAsync(emax, 0, (size_t)NN * 2 * 4, stream);
    hipMemsetAsync(esum, 0, (size_t)NN * 2 * 4, stream);
    k_emax<<<enblk, b256, 0, stream>>>(src, dst, a_s, a_d, emax);
    k_esum<<<enblk, b256, 0, stream>>>(src, dst, a_s, a_d, emax, esum);
    hipMemsetAsync(C, 0, (size_t)NN * HD * 4, stream);
    k_gat_scatter<<<wnblk, b256, 0, stream>>>(src, dst, a_s, a_d, emax, esum, X, C);
    k_gat_fin<<<NN, b64, 0, stream>>>(C, gat_b, B);

    // final SAGE: B -> out
    hipMemsetAsync(A, 0, (size_t)NN * HD * 4, stream);
    k_scatter64<<<wblk, b256, 0, stream>>>(src, dst, B, A);
    k_final<<<NN, b64, 0, stream>>>(A, B, deg, f_wl, f_bl, f_wr, out);
}